// Round 6
// baseline (113.586 us; speedup 1.0000x reference)
//
#include <hip/hip_runtime.h>
#include <math.h>

// Problem constants
#define B_  2
#define L_  512
#define DM_ 256
#define H_  4
#define DK_ 64
#define DV_ 64
#define T_  8
#define PW_ 8

typedef unsigned int uint;

// ---------------------------------------------------------------------------
// bf16 helpers (manual RNE pack, bit-shift unpack)
__device__ __forceinline__ unsigned short f2b(float x) {
    uint u = __float_as_uint(x);
    u += 0x7fffu + ((u >> 16) & 1u);
    return (unsigned short)(u >> 16);
}
__device__ __forceinline__ float bl(uint u)  { return __uint_as_float(u << 16); }
__device__ __forceinline__ float bh_(uint u) { return __uint_as_float(u & 0xffff0000u); }

// ---------------------------------------------------------------------------
// Fast exact-GELU: erf via Abramowitz-Stegun 7.1.26 (|err| <= 1.5e-7).
__device__ __forceinline__ float gelu_fast(float x) {
    const float z  = x * 0.70710678118654752440f;
    const float az = fabsf(z);
    const float t  = __builtin_amdgcn_rcpf(fmaf(0.3275911f, az, 1.0f));
    float p = fmaf(t, 1.061405429f, -1.453152027f);
    p = fmaf(t, p, 1.421413741f);
    p = fmaf(t, p, -0.284496736f);
    p = fmaf(t, p, 0.254829592f);
    p *= t;
    const float e  = __expf(-az * az);
    float er = fmaf(-p, e, 1.0f);
    er = copysignf(er, z);
    return 0.5f * x * (1.0f + er);
}

// phi MLP, params in registers (attn): w0r/b0r/b1r/wfr[8] + bfv; W1 via LDS broadcast
__device__ __forceinline__ float phi_eval_u(
        const float w0r[8], const float b0r[8], const float4* __restrict__ W14,
        const float b1r[8], const float wfr[8], float bfv, float delta) {
    float h1[PW_];
#pragma unroll
    for (int w = 0; w < PW_; ++w)
        h1[w] = gelu_fast(fmaf(delta, w0r[w], b0r[w]));
    float out = bfv;
#pragma unroll
    for (int u = 0; u < PW_; ++u) {
        const float4 c0 = W14[u * 2];
        const float4 c1 = W14[u * 2 + 1];
        float a = b1r[u];
        a = fmaf(c0.x, h1[0], a); a = fmaf(c0.y, h1[1], a);
        a = fmaf(c0.z, h1[2], a); a = fmaf(c0.w, h1[3], a);
        a = fmaf(c1.x, h1[4], a); a = fmaf(c1.y, h1[5], a);
        a = fmaf(c1.z, h1[6], a); a = fmaf(c1.w, h1[7], a);
        out = fmaf(wfr[u], gelu_fast(a), out);
    }
    return out;
}

// phi MLP, params from LDS (phik): P = [w0 0:8 | b0 8:16 | b1 16:24 | wf 24:32 | bf 32]
__device__ __forceinline__ float phi_eval_p(
        const float* __restrict__ P, const float4* __restrict__ W14, float delta) {
    float h1[PW_];
#pragma unroll
    for (int w = 0; w < PW_; ++w)
        h1[w] = gelu_fast(fmaf(delta, P[w], P[8 + w]));
    float out = P[32];
#pragma unroll
    for (int u = 0; u < PW_; ++u) {
        const float4 c0 = W14[u * 2];
        const float4 c1 = W14[u * 2 + 1];
        float a = P[16 + u];
        a = fmaf(c0.x, h1[0], a); a = fmaf(c0.y, h1[1], a);
        a = fmaf(c0.z, h1[2], a); a = fmaf(c0.w, h1[3], a);
        a = fmaf(c1.x, h1[4], a); a = fmaf(c1.y, h1[5], a);
        a = fmaf(c1.z, h1[6], a); a = fmaf(c1.w, h1[7], a);
        out = fmaf(P[24 + u], gelu_fast(a), out);
    }
    return out;
}

// ---------------------------------------------------------------------------
// Fused LN + 3 projections. seg 0: qh(f32) = LN(q)@Wq ; seg 1: khT(bf16, layout
// [bh][d8][j]{8 bf16}) = k@Wk ; seg 2: vh4(bf16, [bh][j4][d]{4 bf16}) = v@Wv.
__global__ __launch_bounds__(256) void qkv_kernel(
        const float* __restrict__ q, const float* __restrict__ k,
        const float* __restrict__ v, const float* __restrict__ ln_g,
        const float* __restrict__ ln_b, const float* __restrict__ Wq,
        const float* __restrict__ Wk, const float* __restrict__ Wv,
        float* __restrict__ qh, uint* __restrict__ khT, uint* __restrict__ vh4) {
    __shared__ __align__(16) float xr[8][DM_];
    const int tid = threadIdx.x;
    const int seg = blockIdx.x >> 7;
    const int row0 = (blockIdx.x & 127) * 8;
    const int b = row0 >> 9;
    const int lrow0 = row0 & (L_ - 1);
    const float* src = seg == 0 ? q : (seg == 1 ? k : v);
    const float* W   = seg == 0 ? Wq : (seg == 1 ? Wk : Wv);
    for (int x = tid; x < 8 * DM_; x += 256)
        xr[x >> 8][x & 255] = src[(size_t)row0 * DM_ + x];
    __syncthreads();
    if (seg == 0) {   // LayerNorm the 8 staged rows (4 waves x 2 rows)
        const int lane = tid & 63, wv = tid >> 6;
#pragma unroll
        for (int rr = 0; rr < 2; ++rr) {
            const int r = wv * 2 + rr;
            float x0 = xr[r][lane], x1 = xr[r][lane + 64];
            float x2 = xr[r][lane + 128], x3 = xr[r][lane + 192];
            float s = x0 + x1 + x2 + x3;
#pragma unroll
            for (int off = 32; off; off >>= 1) s += __shfl_xor(s, off);
            const float mean = s * (1.0f / 256.0f);
            x0 -= mean; x1 -= mean; x2 -= mean; x3 -= mean;
            float s2 = x0 * x0 + x1 * x1 + x2 * x2 + x3 * x3;
#pragma unroll
            for (int off = 32; off; off >>= 1) s2 += __shfl_xor(s2, off);
            const float rstd = rsqrtf(s2 * (1.0f / 256.0f) + 1e-6f);
            xr[r][lane]       = x0 * rstd * ln_g[lane]       + ln_b[lane];
            xr[r][lane + 64]  = x1 * rstd * ln_g[lane + 64]  + ln_b[lane + 64];
            xr[r][lane + 128] = x2 * rstd * ln_g[lane + 128] + ln_b[lane + 128];
            xr[r][lane + 192] = x3 * rstd * ln_g[lane + 192] + ln_b[lane + 192];
        }
        __syncthreads();
    }
    float acc[8] = {0, 0, 0, 0, 0, 0, 0, 0};
#pragma unroll 4
    for (int kk = 0; kk < DM_; ++kk) {
        const float w = W[(size_t)kk * DM_ + tid];
#pragma unroll
        for (int r = 0; r < 8; ++r) acc[r] = fmaf(xr[r][kk], w, acc[r]);
    }
    if (seg == 0) {
#pragma unroll
        for (int r = 0; r < 8; ++r)
            qh[(size_t)(row0 + r) * DM_ + tid] = acc[r];
    } else if (seg == 2) {
        // pack 4 rows (bf16) per uint2: vh4[(bh*128 + j4)*64 + d]
        const int h = tid >> 6, d = tid & 63;
        const int bh = b * H_ + h;
#pragma unroll
        for (int rq = 0; rq < 2; ++rq) {
            uint2 w2;
            w2.x = (uint)f2b(acc[4 * rq])     | ((uint)f2b(acc[4 * rq + 1]) << 16);
            w2.y = (uint)f2b(acc[4 * rq + 2]) | ((uint)f2b(acc[4 * rq + 3]) << 16);
            reinterpret_cast<uint2*>(vh4)[((size_t)bh * 128 + (lrow0 >> 2) + rq) * 64 + d] = w2;
        }
    } else {
        // bf16 transpose via LDS: khT[((bh*8)+d8)*512 + j] = uint4 of 8 bf16 along d
        __syncthreads();   // xr reads done
        unsigned short* buf = reinterpret_cast<unsigned short*>(&xr[0][0]); // [c][8]
        {
            uint4 w4;
            w4.x = (uint)f2b(acc[0]) | ((uint)f2b(acc[1]) << 16);
            w4.y = (uint)f2b(acc[2]) | ((uint)f2b(acc[3]) << 16);
            w4.z = (uint)f2b(acc[4]) | ((uint)f2b(acc[5]) << 16);
            w4.w = (uint)f2b(acc[6]) | ((uint)f2b(acc[7]) << 16);
            reinterpret_cast<uint4*>(buf)[tid] = w4;
        }
        __syncthreads();
        const int jl = tid & 7, d8g = tid >> 3;  // d8g 0..31
        unsigned short e[8];
#pragma unroll
        for (int ee = 0; ee < 8; ++ee)
            e[ee] = buf[(d8g * 8 + ee) * 8 + jl];
        uint4 o;
        o.x = (uint)e[0] | ((uint)e[1] << 16);
        o.y = (uint)e[2] | ((uint)e[3] << 16);
        o.z = (uint)e[4] | ((uint)e[5] << 16);
        o.w = (uint)e[6] | ((uint)e[7] << 16);
        const int h2 = d8g >> 3, d8 = d8g & 7;
        reinterpret_cast<uint4*>(khT)[((size_t)(b * H_ + h2) * 8 + d8) * L_ + lrow0 + jl] = o;
    }
}

// ---------------------------------------------------------------------------
// phiK table, tiled: block = (bh, 64-col tile jt, 64-row chunk ic >= jt).
// Column type is uniform per column; output written as coalesced float4 tiles.
__global__ __launch_bounds__(256) void phik_kernel(
        const float* __restrict__ t_in, const int* __restrict__ c,
        const float* __restrict__ W0, const float* __restrict__ b0,
        const float* __restrict__ W1, const float* __restrict__ b1,
        const float* __restrict__ Wf, const float* __restrict__ bfp,
        float* __restrict__ pkT) {
    __shared__ __align__(16) float W1s[T_ * 64];
    __shared__ __align__(16) float Ps[T_ * 36];
    __shared__ __align__(16) float tile[64 * 68];
    const int tid = threadIdx.x, lane = tid & 63, wv = tid >> 6;
    const int bh = blockIdx.x & 7;
    const int tix = blockIdx.x >> 3;
    const int b = bh >> 2, h = bh & 3;
    int jt = 0, rr = tix;
    while (rr >= 8 - jt) { rr -= 8 - jt; ++jt; }
    const int ic = jt + rr;
    const int j0 = jt * 64, i0 = ic * 64;

    for (int x = tid; x < T_ * 64; x += 256)
        W1s[x] = W1[((x >> 6) * H_ + h) * 64 + (x & 63)];
    for (int x = tid; x < T_ * 36; x += 256) {
        const int t = x / 36, o = x % 36;
        if (o < 33) {
            float val;
            const int th = t * H_ + h;
            if (o < 8)       val = W0[th * 8 + o];
            else if (o < 16) val = b0[th * 8 + (o - 8)];
            else if (o < 24) val = b1[th * 8 + (o - 16)];
            else if (o < 32) val = Wf[th * 8 + (o - 24)];
            else             val = bfp[th];
            Ps[x] = val;
        }
    }
    __syncthreads();

    const float tval = t_in[b * L_ + i0 + lane];
    const int irow = i0 + lane;
    for (int cc = 0; cc < 16; ++cc) {
        const int j = j0 + wv * 16 + cc;
        const int cw = c[b * L_ + j];
        const bool vj = (cw < T_);
        const int ct = min(max(cw, 0), T_ - 1);
        const float tj = t_in[b * L_ + j];
        const float4* W14 = reinterpret_cast<const float4*>(&W1s[ct * 64]);
        const float pv = phi_eval_p(&Ps[ct * 36], W14, tval - tj);
        tile[lane * 68 + wv * 16 + cc] = (vj && irow >= j) ? pv : 0.0f;
    }
    __syncthreads();
    const int ii = tid >> 2, cg = (tid & 3) * 16;
    float* dst = pkT + ((size_t)bh * L_ + i0 + ii) * L_ + j0 + cg;
#pragma unroll
    for (int e4 = 0; e4 < 4; ++e4) {
        const float4 vv = *reinterpret_cast<const float4*>(&tile[ii * 68 + cg + e4 * 4]);
        *reinterpret_cast<float4*>(dst + e4 * 4) = vv;
    }
}

// ---------------------------------------------------------------------------
// Attention: one wave = balanced row pair (i0=p, i1=511-p) for one (b,h).
// K bf16 (khT), V bf16 (vh4), scores/pk in registers, e*pk row in LDS.
__global__ __launch_bounds__(64) void attn_kernel(
        const float* __restrict__ qh, const uint* __restrict__ khT,
        const uint* __restrict__ vh4, const float* __restrict__ t_in,
        const int* __restrict__ c, const float* __restrict__ W0,
        const float* __restrict__ b0, const float* __restrict__ W1,
        const float* __restrict__ b1, const float* __restrict__ Wf,
        const float* __restrict__ bfp, const float* __restrict__ pkT,
        float* __restrict__ oh) {
    __shared__ __align__(16) float W1s[2][64];
    __shared__ __align__(16) uint qs_u[64];   // [2 rows][32 packed q pairs]
    __shared__ __align__(16) float sw[2][516];

    const int lane = threadIdx.x;
    const int g = blockIdx.x;
    const int p = g >> 3;                 // 0..255
    const int bh = g & 7;
    const int b = bh >> 2, h = bh & 3;
    const int i0 = p, i1 = L_ - 1 - p;
    const float* tbase = t_in + b * L_;

    // --- types/params for both rows ---
    const int cw0 = c[b * L_ + i0], cw1 = c[b * L_ + i1];
    const bool vi0 = (cw0 < T_), vi1 = (cw1 < T_);
    const int base0 = __builtin_amdgcn_readfirstlane((min(max(cw0, 0), T_ - 1)) * H_ + h);
    const int base1 = __builtin_amdgcn_readfirstlane((min(max(cw1, 0), T_ - 1)) * H_ + h);
    W1s[0][lane] = W1[base0 * 64 + lane];
    W1s[1][lane] = W1[base1 * 64 + lane];
    float w0r0[8], b0r0[8], b1r0[8], wfr0[8];
    float w0r1[8], b0r1[8], b1r1[8], wfr1[8];
#pragma unroll
    for (int w = 0; w < 8; ++w) {
        w0r0[w] = W0[base0 * 8 + w]; b0r0[w] = b0[base0 * 8 + w];
        b1r0[w] = b1[base0 * 8 + w]; wfr0[w] = Wf[base0 * 8 + w];
        w0r1[w] = W0[base1 * 8 + w]; b0r1[w] = b0[base1 * 8 + w];
        b1r1[w] = b1[base1 * 8 + w]; wfr1[w] = Wf[base1 * 8 + w];
    }
    const float bfv0 = bfp[base0], bfv1 = bfp[base1];
    // --- stage q rows packed bf16 ---
    {
        const int r = lane >> 5, d2 = lane & 31;
        const int ir = r ? i1 : i0;
        const float2 qv = *reinterpret_cast<const float2*>(
            qh + (size_t)(b * L_ + ir) * DM_ + h * DK_ + 2 * d2);
        qs_u[r * 32 + d2] = (uint)f2b(qv.x) | ((uint)f2b(qv.y) << 16);
    }
    __syncthreads();

    const float4* W14_0 = reinterpret_cast<const float4*>(&W1s[0][0]);
    const float4* W14_1 = reinterpret_cast<const float4*>(&W1s[1][0]);
    const uint4* qsu4 = reinterpret_cast<const uint4*>(qs_u);
    const uint4* kT4 = reinterpret_cast<const uint4*>(khT) + (size_t)bh * 8 * L_;
    const float* pkrow0 = pkT + ((size_t)bh * L_ + i0) * L_;
    const float* pkrow1 = pkT + ((size_t)bh * L_ + i1) * L_;
    const float ti0 = tbase[i0], ti1 = tbase[i1];
    const int t0max = i0 >> 6, t1max = i1 >> 6;

    // ---- pass 1: scores + pk in registers, tile-sequential -----------------
    float s0r[8], s1r[8], p0r[8], p1r[8];
#pragma unroll
    for (int t = 0; t < 8; ++t) {
        s0r[t] = -INFINITY; s1r[t] = -INFINITY; p0r[t] = 0.0f; p1r[t] = 0.0f;
    }
#pragma unroll
    for (int t = 0; t < 8; ++t) {
        if (t > t1max) continue;
        const int j = t * 64 + lane;
        const float tj = tbase[j];
        float dot0 = 0.0f, dot1 = 0.0f;
#pragma unroll
        for (int d8 = 0; d8 < 8; ++d8) {
            const uint4 ku = kT4[(size_t)d8 * L_ + j];
            const float kf0 = bl(ku.x), kf1 = bh_(ku.x), kf2 = bl(ku.y), kf3 = bh_(ku.y);
            const float kf4 = bl(ku.z), kf5 = bh_(ku.z), kf6 = bl(ku.w), kf7 = bh_(ku.w);
            const uint4 q1u = qsu4[8 + d8];
            dot1 = fmaf(bl(q1u.x), kf0, fmaf(bh_(q1u.x), kf1,
                   fmaf(bl(q1u.y), kf2, fmaf(bh_(q1u.y), kf3, dot1))));
            dot1 = fmaf(bl(q1u.z), kf4, fmaf(bh_(q1u.z), kf5,
                   fmaf(bl(q1u.w), kf6, fmaf(bh_(q1u.w), kf7, dot1))));
            if (t <= t0max) {
                const uint4 q0u = qsu4[d8];
                dot0 = fmaf(bl(q0u.x), kf0, fmaf(bh_(q0u.x), kf1,
                       fmaf(bl(q0u.y), kf2, fmaf(bh_(q0u.y), kf3, dot0))));
                dot0 = fmaf(bl(q0u.z), kf4, fmaf(bh_(q0u.z), kf5,
                       fmaf(bl(q0u.w), kf6, fmaf(bh_(q0u.w), kf7, dot0))));
            }
        }
        const float pk1v = pkrow1[j];
        const float pq1 = vi1 ? phi_eval_u(w0r1, b0r1, W14_1, b1r1, wfr1, bfv1, ti1 - tj)
                              : 0.0f;
        if (j <= i1) { s1r[t] = dot1 * pq1 * pk1v * 0.125f; p1r[t] = pk1v; }
        if (t <= t0max) {
            const float pk0v = pkrow0[j];
            const float pq0 = vi0 ? phi_eval_u(w0r0, b0r0, W14_0, b1r0, wfr0, bfv0, ti0 - tj)
                                  : 0.0f;
            if (j <= i0) { s0r[t] = dot0 * pq0 * pk0v * 0.125f; p0r[t] = pk0v; }
        }
    }

    // ---- softmax per row (register + shfl) ---------------------------------
    float m0 = -INFINITY, m1 = -INFINITY;
#pragma unroll
    for (int t = 0; t < 8; ++t) { m0 = fmaxf(m0, s0r[t]); m1 = fmaxf(m1, s1r[t]); }
#pragma unroll
    for (int off = 32; off; off >>= 1) {
        m0 = fmaxf(m0, __shfl_xor(m0, off));
        m1 = fmaxf(m1, __shfl_xor(m1, off));
    }
    float ls0 = 0.0f, ls1 = 0.0f;
#pragma unroll
    for (int t = 0; t < 8; ++t) {
        if (t <= t1max) {
            const float e = __expf(s1r[t] - m1);   // exp(-inf)=0 masks j>i1
            ls1 += e;
            const int j = t * 64 + lane;
            if (j <= i1) sw[1][j] = e * p1r[t];
        }
        if (t <= t0max) {
            const float e = __expf(s0r[t] - m0);
            ls0 += e;
            const int j = t * 64 + lane;
            if (j <= i0) sw[0][j] = e * p0r[t];
        }
    }
#pragma unroll
    for (int off = 32; off; off >>= 1) {
        ls0 += __shfl_xor(ls0, off);
        ls1 += __shfl_xor(ls1, off);
    }
    if (lane < 3) {            // zero-pad to multiple-of-4 for float4 PV reads
        sw[0][i0 + 1 + lane] = 0.0f;
        sw[1][i1 + 1 + lane] = 0.0f;
    }
    __syncthreads();

    // ---- PV: lane = d, bf16 V (4 j per uint2), float4 weight broadcasts ----
    const int j4max0 = i0 >> 2, j4max1 = i1 >> 2;
    const uint2* vb = reinterpret_cast<const uint2*>(vh4) + (size_t)bh * 128 * 64 + lane;
    float acc0 = 0.0f, acc1 = 0.0f;
    for (int j4 = 0; j4 <= j4max1; ++j4) {
        const uint2 u = vb[(size_t)j4 * 64];
        const float f0 = bl(u.x), f1 = bh_(u.x), f2 = bl(u.y), f3 = bh_(u.y);
        const float4 w1 = *reinterpret_cast<const float4*>(&sw[1][j4 * 4]);
        acc1 = fmaf(w1.x, f0, fmaf(w1.y, f1, fmaf(w1.z, f2, fmaf(w1.w, f3, acc1))));
        if (j4 <= j4max0) {
            const float4 w0 = *reinterpret_cast<const float4*>(&sw[0][j4 * 4]);
            acc0 = fmaf(w0.x, f0, fmaf(w0.y, f1, fmaf(w0.z, f2, fmaf(w0.w, f3, acc0))));
        }
    }
    oh[(size_t)(b * L_ + i0) * DM_ + h * DV_ + lane] = vi0 ? acc0 / ls0 : 0.0f;
    oh[(size_t)(b * L_ + i1) * DM_ + h * DV_ + lane] = vi1 ? acc1 / ls1 : 0.0f;
}

// ---------------------------------------------------------------------------
// out[row, n] = sum_k oh[row, k] * Wo[k, n] + q[row, n], 4 rows per block.
__global__ __launch_bounds__(256) void out4_kernel(const float* __restrict__ oh,
                                                   const float* __restrict__ Wo,
                                                   const float* __restrict__ q,
                                                   float* __restrict__ out) {
    __shared__ __align__(16) float xr[4][DM_];
    const int tid = threadIdx.x;
    const int row0 = blockIdx.x * 4;
    for (int x = tid; x < 4 * DM_; x += 256)
        xr[x >> 8][x & 255] = oh[(size_t)row0 * DM_ + x];
    __syncthreads();
    float acc[4] = {0, 0, 0, 0};
#pragma unroll 4
    for (int kk = 0; kk < DM_; ++kk) {
        const float w = Wo[(size_t)kk * DM_ + tid];
#pragma unroll
        for (int r = 0; r < 4; ++r) acc[r] = fmaf(xr[r][kk], w, acc[r]);
    }
#pragma unroll
    for (int r = 0; r < 4; ++r)
        out[(size_t)(row0 + r) * DM_ + tid] = acc[r] + q[(size_t)(row0 + r) * DM_ + tid];
}

// ---------------------------------------------------------------------------
extern "C" void kernel_launch(void* const* d_in, const int* in_sizes, int n_in,
                              void* d_out, int out_size, void* d_ws, size_t ws_size,
                              hipStream_t stream) {
    const float* q    = (const float*)d_in[0];
    const float* k    = (const float*)d_in[1];
    const float* v    = (const float*)d_in[2];
    const float* t_in = (const float*)d_in[3];
    const int*   c    = (const int*)d_in[4];
    // d_in[5] = mask: fixed causal triu, never read
    const float* ln_g = (const float*)d_in[6];
    const float* ln_b = (const float*)d_in[7];
    const float* Wq   = (const float*)d_in[8];
    const float* Wk   = (const float*)d_in[9];
    const float* Wv   = (const float*)d_in[10];
    const float* Wo   = (const float*)d_in[11];
    const float* W0   = (const float*)d_in[12];
    const float* b0   = (const float*)d_in[13];
    const float* W1   = (const float*)d_in[14];
    const float* b1   = (const float*)d_in[15];
    const float* Wf   = (const float*)d_in[16];
    const float* bf   = (const float*)d_in[17];
    float* outp = (float*)d_out;

    const size_t NROW = (size_t)B_ * L_;       // 1024
    const size_t SZ   = NROW * DM_;            // 262144 floats
    float* ws = (float*)d_ws;
    float* qh   = ws;                                  // 262144 f
    uint*  khT  = (uint*)(ws + SZ);                    // 131072 u32
    uint*  vh4  = (uint*)(ws + SZ + 131072);           // 131072 u32
    float* oh   = ws + SZ + 262144;                    // 262144 f
    float* pkT  = ws + 2 * SZ + 262144;                // 2097152 f (8 MB)

    qkv_kernel<<<dim3(384), dim3(256), 0, stream>>>(q, k, v, ln_g, ln_b,
                                                    Wq, Wk, Wv, qh, khT, vh4);
    phik_kernel<<<dim3(288), dim3(256), 0, stream>>>(
        t_in, c, W0, b0, W1, b1, Wf, bf, pkT);
    attn_kernel<<<dim3(2048), dim3(64), 0, stream>>>(
        qh, khT, vh4, t_in, c, W0, b0, W1, b1, Wf, bf, pkT, oh);
    out4_kernel<<<dim3(NROW / 4), dim3(256), 0, stream>>>(oh, Wo, q, outp);
}

// Round 7
// 88.112 us; speedup vs baseline: 1.2891x; 1.2891x over previous
//
#include <hip/hip_runtime.h>
#include <math.h>

// Problem constants
#define B_  2
#define L_  512
#define DM_ 256
#define H_  4
#define DK_ 64
#define DV_ 64
#define T_  8
#define PW_ 8

typedef unsigned int uint;

// ---------------------------------------------------------------------------
// bf16 helpers (manual RNE pack, bit-shift unpack)
__device__ __forceinline__ unsigned short f2b(float x) {
    uint u = __float_as_uint(x);
    u += 0x7fffu + ((u >> 16) & 1u);
    return (unsigned short)(u >> 16);
}
__device__ __forceinline__ float bl(uint u)  { return __uint_as_float(u << 16); }
__device__ __forceinline__ float bh_(uint u) { return __uint_as_float(u & 0xffff0000u); }

// ---------------------------------------------------------------------------
// Fast exact-GELU: erf via Abramowitz-Stegun 7.1.26 (|err| <= 1.5e-7).
__device__ __forceinline__ float gelu_fast(float x) {
    const float z  = x * 0.70710678118654752440f;
    const float az = fabsf(z);
    const float t  = __builtin_amdgcn_rcpf(fmaf(0.3275911f, az, 1.0f));
    float p = fmaf(t, 1.061405429f, -1.453152027f);
    p = fmaf(t, p, 1.421413741f);
    p = fmaf(t, p, -0.284496736f);
    p = fmaf(t, p, 0.254829592f);
    p *= t;
    const float e  = __expf(-az * az);
    float er = fmaf(-p, e, 1.0f);
    er = copysignf(er, z);
    return 0.5f * x * (1.0f + er);
}

// phi MLP, params in registers: w0r/b0r/b1r/wfr[8] + bfv; W1 via LDS broadcast
__device__ __forceinline__ float phi_eval_u(
        const float w0r[8], const float b0r[8], const float4* __restrict__ W14,
        const float b1r[8], const float wfr[8], float bfv, float delta) {
    float h1[PW_];
#pragma unroll
    for (int w = 0; w < PW_; ++w)
        h1[w] = gelu_fast(fmaf(delta, w0r[w], b0r[w]));
    float out = bfv;
#pragma unroll
    for (int u = 0; u < PW_; ++u) {
        const float4 c0 = W14[u * 2];
        const float4 c1 = W14[u * 2 + 1];
        float a = b1r[u];
        a = fmaf(c0.x, h1[0], a); a = fmaf(c0.y, h1[1], a);
        a = fmaf(c0.z, h1[2], a); a = fmaf(c0.w, h1[3], a);
        a = fmaf(c1.x, h1[4], a); a = fmaf(c1.y, h1[5], a);
        a = fmaf(c1.z, h1[6], a); a = fmaf(c1.w, h1[7], a);
        out = fmaf(wfr[u], gelu_fast(a), out);
    }
    return out;
}

// phi MLP, params from LDS: P = [w0 0:8 | b0 8:16 | b1 16:24 | wf 24:32 | bf 32]
__device__ __forceinline__ float phi_eval_p(
        const float* __restrict__ P, const float4* __restrict__ W14, float delta) {
    float h1[PW_];
#pragma unroll
    for (int w = 0; w < PW_; ++w)
        h1[w] = gelu_fast(fmaf(delta, P[w], P[8 + w]));
    float out = P[32];
#pragma unroll
    for (int u = 0; u < PW_; ++u) {
        const float4 c0 = W14[u * 2];
        const float4 c1 = W14[u * 2 + 1];
        float a = P[16 + u];
        a = fmaf(c0.x, h1[0], a); a = fmaf(c0.y, h1[1], a);
        a = fmaf(c0.z, h1[2], a); a = fmaf(c0.w, h1[3], a);
        a = fmaf(c1.x, h1[4], a); a = fmaf(c1.y, h1[5], a);
        a = fmaf(c1.z, h1[6], a); a = fmaf(c1.w, h1[7], a);
        out = fmaf(P[24 + u], gelu_fast(a), out);
    }
    return out;
}

// ---------------------------------------------------------------------------
// Fused LN + 3 projections. seg 0: qh(f32) = LN(q)@Wq ; seg 1: khT(f32,
// interleaved [bh][d4][j][4]) = k@Wk ; seg 2: vh4(bf16, [bh][j4][d]{4}) = v@Wv.
__global__ __launch_bounds__(256) void qkv_kernel(
        const float* __restrict__ q, const float* __restrict__ k,
        const float* __restrict__ v, const float* __restrict__ ln_g,
        const float* __restrict__ ln_b, const float* __restrict__ Wq,
        const float* __restrict__ Wk, const float* __restrict__ Wv,
        float* __restrict__ qh, float* __restrict__ khT, uint* __restrict__ vh4) {
    __shared__ __align__(16) float xr[8][DM_];
    const int tid = threadIdx.x;
    const int seg = blockIdx.x >> 7;
    const int row0 = (blockIdx.x & 127) * 8;
    const int b = row0 >> 9;
    const int lrow0 = row0 & (L_ - 1);
    const float* src = seg == 0 ? q : (seg == 1 ? k : v);
    const float* W   = seg == 0 ? Wq : (seg == 1 ? Wk : Wv);
    for (int x = tid; x < 8 * DM_; x += 256)
        xr[x >> 8][x & 255] = src[(size_t)row0 * DM_ + x];
    __syncthreads();
    if (seg == 0) {   // LayerNorm the 8 staged rows (4 waves x 2 rows)
        const int lane = tid & 63, wv = tid >> 6;
#pragma unroll
        for (int rr = 0; rr < 2; ++rr) {
            const int r = wv * 2 + rr;
            float x0 = xr[r][lane], x1 = xr[r][lane + 64];
            float x2 = xr[r][lane + 128], x3 = xr[r][lane + 192];
            float s = x0 + x1 + x2 + x3;
#pragma unroll
            for (int off = 32; off; off >>= 1) s += __shfl_xor(s, off);
            const float mean = s * (1.0f / 256.0f);
            x0 -= mean; x1 -= mean; x2 -= mean; x3 -= mean;
            float s2 = x0 * x0 + x1 * x1 + x2 * x2 + x3 * x3;
#pragma unroll
            for (int off = 32; off; off >>= 1) s2 += __shfl_xor(s2, off);
            const float rstd = rsqrtf(s2 * (1.0f / 256.0f) + 1e-6f);
            xr[r][lane]       = x0 * rstd * ln_g[lane]       + ln_b[lane];
            xr[r][lane + 64]  = x1 * rstd * ln_g[lane + 64]  + ln_b[lane + 64];
            xr[r][lane + 128] = x2 * rstd * ln_g[lane + 128] + ln_b[lane + 128];
            xr[r][lane + 192] = x3 * rstd * ln_g[lane + 192] + ln_b[lane + 192];
        }
        __syncthreads();
    }
    float acc[8] = {0, 0, 0, 0, 0, 0, 0, 0};
#pragma unroll 4
    for (int kk = 0; kk < DM_; ++kk) {
        const float w = W[(size_t)kk * DM_ + tid];
#pragma unroll
        for (int r = 0; r < 8; ++r) acc[r] = fmaf(xr[r][kk], w, acc[r]);
    }
    if (seg == 0) {
#pragma unroll
        for (int r = 0; r < 8; ++r)
            qh[(size_t)(row0 + r) * DM_ + tid] = acc[r];
    } else if (seg == 1) {
        // khT[((bh)*16 + d4) * (L*4) + j*4 + e]  (fp32)
        const int h = tid >> 6, dd = tid & 63, d4 = dd >> 2, e = dd & 3;
        float* basep = khT + ((size_t)(b * H_ + h) * 16 + d4) * (L_ * 4) + e;
#pragma unroll
        for (int r = 0; r < 8; ++r)
            basep[(size_t)(lrow0 + r) * 4] = acc[r];
    } else {
        // pack 4 rows (bf16) per uint2: vh4[(bh*128 + j4)*64 + d]
        const int h = tid >> 6, d = tid & 63;
        const int bh = b * H_ + h;
#pragma unroll
        for (int rq = 0; rq < 2; ++rq) {
            uint2 w2;
            w2.x = (uint)f2b(acc[4 * rq])     | ((uint)f2b(acc[4 * rq + 1]) << 16);
            w2.y = (uint)f2b(acc[4 * rq + 2]) | ((uint)f2b(acc[4 * rq + 3]) << 16);
            reinterpret_cast<uint2*>(vh4)[((size_t)bh * 128 + (lrow0 >> 2) + rq) * 64 + d] = w2;
        }
    }
}

// ---------------------------------------------------------------------------
// phiK table: pkT[bh][i][j] = phi_{c_j,h}(t_i - t_j) * (c_j < T), lower tri.
// One wave per 64-row x 4-col tile; 4608 waves, 1152 blocks.
// Block: b = blockIdx&1, wave wv handles h = wv, tile t = blockIdx>>1.
__global__ __launch_bounds__(256) void phik_kernel(
        const float* __restrict__ t_in, const int* __restrict__ c,
        const float* __restrict__ W0, const float* __restrict__ b0,
        const float* __restrict__ W1, const float* __restrict__ b1,
        const float* __restrict__ Wf, const float* __restrict__ bfp,
        float* __restrict__ pkT) {
    __shared__ __align__(16) float W1s[4][T_][64];
    __shared__ float Ps[4][T_][34];
    const int tid = threadIdx.x, lane = tid & 63, wv = tid >> 6;
    const int b = blockIdx.x & 1;
    const int h = wv;
    const int bh = b * H_ + h;
    const int t = blockIdx.x >> 1;            // 0..575

    // stage this head's params, all 8 types (per wave)
#pragma unroll
    for (int t8 = 0; t8 < T_; ++t8)
        W1s[wv][t8][lane] = W1[(t8 * H_ + h) * 64 + lane];
    for (int x = lane; x < T_ * 33; x += 64) {
        const int t8 = x / 33, o = x % 33;
        const int th = t8 * H_ + h;
        float val;
        if (o < 8)       val = W0[th * 8 + o];
        else if (o < 16) val = b0[th * 8 + (o - 8)];
        else if (o < 24) val = b1[th * 8 + (o - 16)];
        else if (o < 32) val = Wf[th * 8 + (o - 24)];
        else             val = bfp[th];
        Ps[wv][t8][o] = val;
    }
    __syncthreads();

    // tile t -> (jc4, ir): col-chunk of 4, row-chunk of 64, ir >= jc4>>4
    int rem = t, g = 0;
#pragma unroll
    for (int gg = 0; gg < 8; ++gg) {
        const int tot = 16 * (8 - gg);
        if (rem >= tot) { rem -= tot; g = gg + 1; }
        else break;
    }
    const int jc4 = 16 * g + rem / (8 - g);
    const int ir  = g + rem % (8 - g);
    const int i = ir * 64 + lane;
    const int j0 = jc4 * 4;
    const float ti = t_in[b * L_ + i];
    float o4[4];
#pragma unroll
    for (int cc = 0; cc < 4; ++cc) {
        const int j = j0 + cc;
        const int cw = c[b * L_ + j];
        const bool vj = (cw < T_);
        const int ct = min(max(cw, 0), T_ - 1);
        const float tj = t_in[b * L_ + j];
        const float val = phi_eval_p(&Ps[wv][ct][0],
                                     reinterpret_cast<const float4*>(&W1s[wv][ct][0]),
                                     ti - tj);
        o4[cc] = (vj && i >= j) ? val : 0.0f;
    }
    float4 o;
    o.x = o4[0]; o.y = o4[1]; o.z = o4[2]; o.w = o4[3];
    *reinterpret_cast<float4*>(&pkT[((size_t)bh * L_ + i) * L_ + j0]) = o;
}

// ---------------------------------------------------------------------------
// Attention partials: wave = (row, bh, segment). 8192 waves, 4/block.
// Flash-style online softmax over the segment's 64-aligned j-tiles.
// Partials: pm[g] (max), pl[g] (sum), pacc[g][64] (unnormalized PV).
__global__ __launch_bounds__(256) void attn_part(
        const float* __restrict__ qh, const float* __restrict__ khT,
        const uint* __restrict__ vh4, const float* __restrict__ t_in,
        const int* __restrict__ c, const float* __restrict__ W0,
        const float* __restrict__ b0, const float* __restrict__ W1,
        const float* __restrict__ b1, const float* __restrict__ Wf,
        const float* __restrict__ bfp, const float* __restrict__ pkT,
        float* __restrict__ pm, float* __restrict__ pl,
        float* __restrict__ pacc) {
    __shared__ __align__(16) float W1s[4][64];
    __shared__ __align__(16) float qs[4][64];
    __shared__ __align__(16) float sw[4][64];

    const int lane = threadIdx.x & 63, wv = threadIdx.x >> 6;
    const int g = blockIdx.x * 4 + wv;        // 0..8191
    const int rowp = g >> 4;                  // same for all 4 waves of a block
    const int bh = (g >> 1) & 7;
    const int seg = g & 1;
    const int b = bh >> 2, h = bh & 3;
    const int i = (L_ - 1) - rowp;            // heavy rows first
    const int n = i + 1;
    const int ntiles = (n + 63) >> 6;
    const int half = ntiles >> 1;
    const int t_lo = seg ? half : 0;
    const int t_hi = seg ? ntiles : half;
    const int hi   = seg ? n : (half << 6);
    const int tmax = ntiles - half;           // uniform loop count in block

    const int row = b * L_ + i;
    const int cw = c[row];
    const bool vi = (cw < T_);
    const int base = __builtin_amdgcn_readfirstlane((min(max(cw, 0), T_ - 1)) * H_ + h);

    W1s[wv][lane] = W1[base * 64 + lane];
    qs[wv][lane]  = qh[(size_t)row * DM_ + h * DK_ + lane];
    float w0r[8], b0r[8], b1r[8], wfr[8];
#pragma unroll
    for (int w = 0; w < 8; ++w) {
        w0r[w] = W0[base * 8 + w]; b0r[w] = b0[base * 8 + w];
        b1r[w] = b1[base * 8 + w]; wfr[w] = Wf[base * 8 + w];
    }
    const float bfv = bfp[base];
    __syncthreads();

    const float4* W14 = reinterpret_cast<const float4*>(&W1s[wv][0]);
    const float4* qs4 = reinterpret_cast<const float4*>(&qs[wv][0]);
    const float4* kT4 = reinterpret_cast<const float4*>(khT) + (size_t)bh * 16 * L_;
    const float* pkrow = pkT + ((size_t)bh * L_ + i) * L_;
    const float* tbase = t_in + b * L_;
    const uint2* vb = reinterpret_cast<const uint2*>(vh4) + (size_t)bh * 128 * 64 + lane;
    const float ti = tbase[i];

    float m_run = -INFINITY, l_lane = 0.0f, acc = 0.0f;
    for (int tt = 0; tt < tmax; ++tt) {
        const int tcur = t_lo + tt;
        const bool live = tcur < t_hi;
        const int jb = tcur << 6;
        const int j = jb + lane;              // j <= 511 always (jb <= 448)
        const bool act = live && (j < hi);
        float s = -INFINITY, pk = 0.0f;
        if (live) {                           // wave-uniform branch
            pk = act ? pkrow[j] : 0.0f;
            const float tj = tbase[j];
            const float pq = vi ? phi_eval_u(w0r, b0r, W14, b1r, wfr, bfv, ti - tj)
                                : 0.0f;
            float dot = 0.0f;
#pragma unroll
            for (int d4 = 0; d4 < 16; ++d4) {
                const float4 kk = kT4[(size_t)d4 * L_ + j];
                const float4 a = qs4[d4];
                dot = fmaf(a.x, kk.x, fmaf(a.y, kk.y, fmaf(a.z, kk.z, fmaf(a.w, kk.w, dot))));
            }
            if (act) s = dot * pq * pk * 0.125f;
        }
        float tm = s;
#pragma unroll
        for (int off = 32; off; off >>= 1) tm = fmaxf(tm, __shfl_xor(tm, off));
        const float m_new = fmaxf(m_run, tm);
        const float scale = (m_new > -1e30f) ? __expf(m_run - m_new) : 0.0f;
        const float e = act ? __expf(s - m_new) : 0.0f;
        l_lane = l_lane * scale + e;
        acc *= scale;
        sw[wv][lane] = e * pk;
        __syncthreads();
        if (live) {
            const int jb4 = jb >> 2;
#pragma unroll
            for (int q4 = 0; q4 < 16; ++q4) {
                const uint2 u = vb[(size_t)(jb4 + q4) * 64];
                const float4 w = *reinterpret_cast<const float4*>(&sw[wv][q4 * 4]);
                acc = fmaf(w.x, bl(u.x), fmaf(w.y, bh_(u.x),
                      fmaf(w.z, bl(u.y), fmaf(w.w, bh_(u.y), acc))));
            }
        }
        m_run = m_new;
        __syncthreads();
    }
#pragma unroll
    for (int off = 32; off; off >>= 1) l_lane += __shfl_xor(l_lane, off);
    pacc[(size_t)g * 64 + lane] = acc;
    if (lane == 0) { pm[g] = m_run; pl[g] = l_lane; }
}

// ---------------------------------------------------------------------------
// Combine partials + output projection + residual, 4 rows per block.
__global__ __launch_bounds__(256) void out4_kernel(
        const float* __restrict__ pm, const float* __restrict__ pl,
        const float* __restrict__ pacc, const int* __restrict__ c,
        const float* __restrict__ Wo, const float* __restrict__ q,
        float* __restrict__ out) {
    __shared__ __align__(16) float xr[4][DM_];
    const int tid = threadIdx.x;
    const int r4 = tid >> 6, d = tid & 63;
    const int row0 = blockIdx.x * 4;
    const int row = row0 + r4;
    const int b = row >> 9, i = row & (L_ - 1);
    const bool vi = (c[row] < T_);
    const int rowp = (L_ - 1) - i;
#pragma unroll
    for (int h = 0; h < H_; ++h) {
        const int g0 = (rowp << 4) | ((b * H_ + h) << 1);
        const float m0 = pm[g0], m1 = pm[g0 + 1];
        const float l0 = pl[g0], l1 = pl[g0 + 1];
        const float M = fmaxf(m0, m1);
        const float e0 = __expf(m0 - M), e1 = __expf(m1 - M);
        const float l = fmaf(l0, e0, l1 * e1);
        const float a0 = pacc[(size_t)g0 * 64 + d];
        const float a1 = pacc[(size_t)(g0 + 1) * 64 + d];
        xr[r4][h * 64 + d] = vi ? fmaf(a0, e0, a1 * e1) / l : 0.0f;
    }
    __syncthreads();
    float acc[4] = {0, 0, 0, 0};
#pragma unroll 4
    for (int kk = 0; kk < DM_; ++kk) {
        const float w = Wo[(size_t)kk * DM_ + tid];
#pragma unroll
        for (int r = 0; r < 4; ++r) acc[r] = fmaf(xr[r][kk], w, acc[r]);
    }
#pragma unroll
    for (int r = 0; r < 4; ++r)
        out[(size_t)(row0 + r) * DM_ + tid] = acc[r] + q[(size_t)(row0 + r) * DM_ + tid];
}

// ---------------------------------------------------------------------------
extern "C" void kernel_launch(void* const* d_in, const int* in_sizes, int n_in,
                              void* d_out, int out_size, void* d_ws, size_t ws_size,
                              hipStream_t stream) {
    const float* q    = (const float*)d_in[0];
    const float* k    = (const float*)d_in[1];
    const float* v    = (const float*)d_in[2];
    const float* t_in = (const float*)d_in[3];
    const int*   c    = (const int*)d_in[4];
    // d_in[5] = mask: fixed causal triu, never read
    const float* ln_g = (const float*)d_in[6];
    const float* ln_b = (const float*)d_in[7];
    const float* Wq   = (const float*)d_in[8];
    const float* Wk   = (const float*)d_in[9];
    const float* Wv   = (const float*)d_in[10];
    const float* Wo   = (const float*)d_in[11];
    const float* W0   = (const float*)d_in[12];
    const float* b0   = (const float*)d_in[13];
    const float* W1   = (const float*)d_in[14];
    const float* b1   = (const float*)d_in[15];
    const float* Wf   = (const float*)d_in[16];
    const float* bf   = (const float*)d_in[17];
    float* outp = (float*)d_out;

    const size_t NROW = (size_t)B_ * L_;       // 1024
    const size_t SZ   = NROW * DM_;            // 262144 floats
    float* ws = (float*)d_ws;
    float* qh   = ws;                          // 262144 f
    float* khT  = ws + SZ;                     // 262144 f
    uint*  vh4  = (uint*)(ws + 2 * SZ);        // 131072 u32
    float* pacc = ws + 2 * SZ + 131072;        // 8192*64 = 524288 f
    float* pm   = pacc + 524288;               // 8192 f
    float* pl   = pm + 8192;                   // 8192 f
    float* pkT  = pl + 8192;                   // 2097152 f (8 MB)

    qkv_kernel<<<dim3(384), dim3(256), 0, stream>>>(q, k, v, ln_g, ln_b,
                                                    Wq, Wk, Wv, qh, khT, vh4);
    phik_kernel<<<dim3(1152), dim3(256), 0, stream>>>(
        t_in, c, W0, b0, W1, b1, Wf, bf, pkT);
    attn_part<<<dim3(2048), dim3(256), 0, stream>>>(
        qh, khT, vh4, t_in, c, W0, b0, W1, b1, Wf, bf, pkT, pm, pl, pacc);
    out4_kernel<<<dim3(256), dim3(256), 0, stream>>>(pm, pl, pacc, c, Wo, q, outp);
}

// Round 8
// 80.350 us; speedup vs baseline: 1.4136x; 1.0966x over previous
//
#include <hip/hip_runtime.h>
#include <math.h>

// Problem constants
#define B_  2
#define L_  512
#define DM_ 256
#define H_  4
#define DK_ 64
#define DV_ 64
#define T_  8
#define PW_ 8

typedef unsigned int uint;

// ---------------------------------------------------------------------------
// bf16 helpers (manual RNE pack, bit-shift unpack)
__device__ __forceinline__ unsigned short f2b(float x) {
    uint u = __float_as_uint(x);
    u += 0x7fffu + ((u >> 16) & 1u);
    return (unsigned short)(u >> 16);
}
__device__ __forceinline__ float bl(uint u)  { return __uint_as_float(u << 16); }
__device__ __forceinline__ float bh_(uint u) { return __uint_as_float(u & 0xffff0000u); }

// ---------------------------------------------------------------------------
// Fast exact-GELU: erf via Abramowitz-Stegun 7.1.26 (|err| <= 1.5e-7).
__device__ __forceinline__ float gelu_fast(float x) {
    const float z  = x * 0.70710678118654752440f;
    const float az = fabsf(z);
    const float t  = __builtin_amdgcn_rcpf(fmaf(0.3275911f, az, 1.0f));
    float p = fmaf(t, 1.061405429f, -1.453152027f);
    p = fmaf(t, p, 1.421413741f);
    p = fmaf(t, p, -0.284496736f);
    p = fmaf(t, p, 0.254829592f);
    p *= t;
    const float e  = __expf(-az * az);
    float er = fmaf(-p, e, 1.0f);
    er = copysignf(er, z);
    return 0.5f * x * (1.0f + er);
}

// phi MLP, params in registers: w0r/b0r/b1r/wfr[8] + bfv; W1 via LDS broadcast
__device__ __forceinline__ float phi_eval_u(
        const float w0r[8], const float b0r[8], const float4* __restrict__ W14,
        const float b1r[8], const float wfr[8], float bfv, float delta) {
    float h1[PW_];
#pragma unroll
    for (int w = 0; w < PW_; ++w)
        h1[w] = gelu_fast(fmaf(delta, w0r[w], b0r[w]));
    float out = bfv;
#pragma unroll
    for (int u = 0; u < PW_; ++u) {
        const float4 c0 = W14[u * 2];
        const float4 c1 = W14[u * 2 + 1];
        float a = b1r[u];
        a = fmaf(c0.x, h1[0], a); a = fmaf(c0.y, h1[1], a);
        a = fmaf(c0.z, h1[2], a); a = fmaf(c0.w, h1[3], a);
        a = fmaf(c1.x, h1[4], a); a = fmaf(c1.y, h1[5], a);
        a = fmaf(c1.z, h1[6], a); a = fmaf(c1.w, h1[7], a);
        out = fmaf(wfr[u], gelu_fast(a), out);
    }
    return out;
}

// phi MLP, params from LDS: P = [w0 0:8 | b0 8:16 | b1 16:24 | wf 24:32 | bf 32]
__device__ __forceinline__ float phi_eval_p(
        const float* __restrict__ P, const float4* __restrict__ W14, float delta) {
    float h1[PW_];
#pragma unroll
    for (int w = 0; w < PW_; ++w)
        h1[w] = gelu_fast(fmaf(delta, P[w], P[8 + w]));
    float out = P[32];
#pragma unroll
    for (int u = 0; u < PW_; ++u) {
        const float4 c0 = W14[u * 2];
        const float4 c1 = W14[u * 2 + 1];
        float a = P[16 + u];
        a = fmaf(c0.x, h1[0], a); a = fmaf(c0.y, h1[1], a);
        a = fmaf(c0.z, h1[2], a); a = fmaf(c0.w, h1[3], a);
        a = fmaf(c1.x, h1[4], a); a = fmaf(c1.y, h1[5], a);
        a = fmaf(c1.z, h1[6], a); a = fmaf(c1.w, h1[7], a);
        out = fmaf(P[24 + u], gelu_fast(a), out);
    }
    return out;
}

// ---------------------------------------------------------------------------
// Fused prep kernel. Blocks [0,1152): phiK table. Blocks [1152,1536): LN+QKV.
//   qh(f32) = LN(q)@Wq ; khT(f32, [bh][d4][j][4]) = k@Wk ;
//   vh4(bf16, [bh][j4][d]{4}) = v@Wv ;
//   pkT[bh][i][j] = phi_{c_j,h}(t_i - t_j) * (c_j < T)  (lower triangle).
__global__ __launch_bounds__(256) void fused_prep(
        const float* __restrict__ q, const float* __restrict__ k,
        const float* __restrict__ v, const float* __restrict__ ln_g,
        const float* __restrict__ ln_b, const float* __restrict__ Wq,
        const float* __restrict__ Wk, const float* __restrict__ Wv,
        const float* __restrict__ t_in, const int* __restrict__ c,
        const float* __restrict__ W0, const float* __restrict__ b0,
        const float* __restrict__ W1, const float* __restrict__ b1,
        const float* __restrict__ Wf, const float* __restrict__ bfp,
        float* __restrict__ qh, float* __restrict__ khT,
        uint* __restrict__ vh4, float* __restrict__ pkT) {
    __shared__ __align__(16) float smem[3264];
    const int tid = threadIdx.x, lane = tid & 63, wv = tid >> 6;

    if (blockIdx.x >= 1152) {
        // ================= QKV part =================
        const int bid = blockIdx.x - 1152;
        float (*xr)[DM_] = reinterpret_cast<float (*)[DM_]>(smem);
        const int seg = bid >> 7;
        const int row0 = (bid & 127) * 8;
        const int b = row0 >> 9;
        const int lrow0 = row0 & (L_ - 1);
        const float* src = seg == 0 ? q : (seg == 1 ? k : v);
        const float* W   = seg == 0 ? Wq : (seg == 1 ? Wk : Wv);
        for (int x = tid; x < 8 * DM_; x += 256)
            xr[x >> 8][x & 255] = src[(size_t)row0 * DM_ + x];
        __syncthreads();
        if (seg == 0) {   // LayerNorm the 8 staged rows (4 waves x 2 rows)
#pragma unroll
            for (int rr = 0; rr < 2; ++rr) {
                const int r = wv * 2 + rr;
                float x0 = xr[r][lane], x1 = xr[r][lane + 64];
                float x2 = xr[r][lane + 128], x3 = xr[r][lane + 192];
                float s = x0 + x1 + x2 + x3;
#pragma unroll
                for (int off = 32; off; off >>= 1) s += __shfl_xor(s, off);
                const float mean = s * (1.0f / 256.0f);
                x0 -= mean; x1 -= mean; x2 -= mean; x3 -= mean;
                float s2 = x0 * x0 + x1 * x1 + x2 * x2 + x3 * x3;
#pragma unroll
                for (int off = 32; off; off >>= 1) s2 += __shfl_xor(s2, off);
                const float rstd = rsqrtf(s2 * (1.0f / 256.0f) + 1e-6f);
                xr[r][lane]       = x0 * rstd * ln_g[lane]       + ln_b[lane];
                xr[r][lane + 64]  = x1 * rstd * ln_g[lane + 64]  + ln_b[lane + 64];
                xr[r][lane + 128] = x2 * rstd * ln_g[lane + 128] + ln_b[lane + 128];
                xr[r][lane + 192] = x3 * rstd * ln_g[lane + 192] + ln_b[lane + 192];
            }
            __syncthreads();
        }
        float acc[8] = {0, 0, 0, 0, 0, 0, 0, 0};
#pragma unroll 4
        for (int kk = 0; kk < DM_; ++kk) {
            const float w = W[(size_t)kk * DM_ + tid];
#pragma unroll
            for (int r = 0; r < 8; ++r) acc[r] = fmaf(xr[r][kk], w, acc[r]);
        }
        if (seg == 0) {
#pragma unroll
            for (int r = 0; r < 8; ++r)
                qh[(size_t)(row0 + r) * DM_ + tid] = acc[r];
        } else if (seg == 1) {
            // khT[((bh)*16 + d4) * (L*4) + j*4 + e]  (fp32)
            const int h = tid >> 6, dd = tid & 63, d4 = dd >> 2, e = dd & 3;
            float* basep = khT + ((size_t)(b * H_ + h) * 16 + d4) * (L_ * 4) + e;
#pragma unroll
            for (int r = 0; r < 8; ++r)
                basep[(size_t)(lrow0 + r) * 4] = acc[r];
        } else {
            // pack 4 rows (bf16) per uint2: vh4[(bh*128 + j4)*64 + d]
            const int h = tid >> 6, d = tid & 63;
            const int bh = b * H_ + h;
#pragma unroll
            for (int rq = 0; rq < 2; ++rq) {
                uint2 w2;
                w2.x = (uint)f2b(acc[4 * rq])     | ((uint)f2b(acc[4 * rq + 1]) << 16);
                w2.y = (uint)f2b(acc[4 * rq + 2]) | ((uint)f2b(acc[4 * rq + 3]) << 16);
                reinterpret_cast<uint2*>(vh4)[((size_t)bh * 128 + (lrow0 >> 2) + rq) * 64 + d] = w2;
            }
        }
    } else {
        // ================= phiK part =================
        float (*W1s)[T_][64] = reinterpret_cast<float (*)[T_][64]>(smem);
        float (*Ps)[T_ * 34] = reinterpret_cast<float (*)[T_ * 34]>(smem + 2048);
        const int b = blockIdx.x & 1;
        const int h = wv;
        const int bh = b * H_ + h;
        const int t = blockIdx.x >> 1;            // 0..575

#pragma unroll
        for (int t8 = 0; t8 < T_; ++t8)
            W1s[wv][t8][lane] = W1[(t8 * H_ + h) * 64 + lane];
        for (int x = lane; x < T_ * 33; x += 64) {
            const int t8 = x / 33, o = x % 33;
            const int th = t8 * H_ + h;
            float val;
            if (o < 8)       val = W0[th * 8 + o];
            else if (o < 16) val = b0[th * 8 + (o - 8)];
            else if (o < 24) val = b1[th * 8 + (o - 16)];
            else if (o < 32) val = Wf[th * 8 + (o - 24)];
            else             val = bfp[th];
            Ps[wv][t8 * 34 + o] = val;
        }
        __syncthreads();

        // tile t -> (jc4, ir): col-chunk of 4, row-chunk of 64, ir >= jc4>>4
        int rem = t, g = 0;
#pragma unroll
        for (int gg = 0; gg < 8; ++gg) {
            const int tot = 16 * (8 - gg);
            if (rem >= tot) { rem -= tot; g = gg + 1; }
            else break;
        }
        const int jc4 = 16 * g + rem / (8 - g);
        const int ir  = g + rem % (8 - g);
        const int i = ir * 64 + lane;
        const int j0 = jc4 * 4;
        const float ti = t_in[b * L_ + i];
        float o4[4];
#pragma unroll
        for (int cc = 0; cc < 4; ++cc) {
            const int j = j0 + cc;
            const int cw = c[b * L_ + j];
            const bool vj = (cw < T_);
            const int ct = min(max(cw, 0), T_ - 1);
            const float tj = t_in[b * L_ + j];
            const float val = phi_eval_p(&Ps[wv][ct * 34],
                                         reinterpret_cast<const float4*>(&W1s[wv][ct][0]),
                                         ti - tj);
            o4[cc] = (vj && i >= j) ? val : 0.0f;
        }
        float4 o;
        o.x = o4[0]; o.y = o4[1]; o.z = o4[2]; o.w = o4[3];
        *reinterpret_cast<float4*>(&pkT[((size_t)bh * L_ + i) * L_ + j0]) = o;
    }
}

// ---------------------------------------------------------------------------
// Attention tiles: ONE WAVE = one (bh, row i, 64-j tile t) unit — perfectly
// uniform work. 18432 waves, 2 per 128-thread block. Writes partial
// (m, l, acc[64]) at [bh][i][t].
__global__ __launch_bounds__(128) void attn_tile(
        const float* __restrict__ qh, const float* __restrict__ khT,
        const uint* __restrict__ vh4, const float* __restrict__ t_in,
        const int* __restrict__ c, const float* __restrict__ W0,
        const float* __restrict__ b0, const float* __restrict__ W1,
        const float* __restrict__ b1, const float* __restrict__ Wf,
        const float* __restrict__ bfp, const float* __restrict__ pkT,
        float* __restrict__ pm, float* __restrict__ pl,
        float* __restrict__ pacc) {
    __shared__ __align__(16) float W1s[2][64];
    __shared__ __align__(16) float qs[2][64];
    __shared__ __align__(16) float sw[2][64];

    const int lane = threadIdx.x & 63, wv = threadIdx.x >> 6;
    const int unit = blockIdx.x * 2 + wv;     // 0..18431
    const int bh = unit & 7;
    const int tix = unit >> 3;                // 0..2303
    const int b = bh >> 2, h = bh & 3;

    // decode tix -> (row group g, row i, tile t): rows in group g have g+1 tiles
    int g = 0;
#pragma unroll
    for (int gg = 1; gg < 8; ++gg)
        if (tix >= 32 * gg * (gg + 1)) g = gg;
    const int rem = tix - 32 * g * (g + 1);
    const int il = rem / (g + 1);
    const int t = rem - il * (g + 1);
    const int i = g * 64 + il;
    const int row = b * L_ + i;

    const float ti = t_in[row];
    const int cw = c[row];
    const bool vi = (cw < T_);
    const int base = __builtin_amdgcn_readfirstlane((min(max(cw, 0), T_ - 1)) * H_ + h);

    W1s[wv][lane] = W1[base * 64 + lane];
    qs[wv][lane]  = qh[(size_t)row * DM_ + h * DK_ + lane];
    float w0r[8], b0r[8], b1r[8], wfr[8];
#pragma unroll
    for (int w = 0; w < 8; ++w) {
        w0r[w] = W0[base * 8 + w]; b0r[w] = b0[base * 8 + w];
        b1r[w] = b1[base * 8 + w]; wfr[w] = Wf[base * 8 + w];
    }
    const float bfv = bfp[base];
    __syncthreads();

    const float4* W14 = reinterpret_cast<const float4*>(&W1s[wv][0]);
    const float4* qs4 = reinterpret_cast<const float4*>(&qs[wv][0]);
    const float4* kT4 = reinterpret_cast<const float4*>(khT) + (size_t)bh * 16 * L_;
    const float* tbase = t_in + b * L_;

    const int jb = t << 6;
    const int j = jb + lane;
    const bool act = (j <= i);

    // score
    const float pk = act ? pkT[((size_t)bh * L_ + i) * L_ + j] : 0.0f;
    const float tj = tbase[j];
    const float pq = vi ? phi_eval_u(w0r, b0r, W14, b1r, wfr, bfv, ti - tj) : 0.0f;
    float dot = 0.0f;
#pragma unroll
    for (int d4 = 0; d4 < 16; ++d4) {
        const float4 kk = kT4[(size_t)d4 * L_ + j];
        const float4 a = qs4[d4];
        dot = fmaf(a.x, kk.x, fmaf(a.y, kk.y, fmaf(a.z, kk.z, fmaf(a.w, kk.w, dot))));
    }
    const float s = act ? dot * pq * pk * 0.125f : -INFINITY;

    // tile softmax partial
    float m = s;
#pragma unroll
    for (int off = 32; off; off >>= 1) m = fmaxf(m, __shfl_xor(m, off));
    const float e = act ? __expf(s - m) : 0.0f;
    float l = e;
#pragma unroll
    for (int off = 32; off; off >>= 1) l += __shfl_xor(l, off);
    sw[wv][lane] = e * pk;
    __syncthreads();

    // PV over this tile: lane = d
    const uint2* vb = reinterpret_cast<const uint2*>(vh4) + (size_t)bh * 128 * 64 + lane;
    const int jb4 = jb >> 2;
    float acc = 0.0f;
#pragma unroll
    for (int q4 = 0; q4 < 16; ++q4) {
        const uint2 u = vb[(size_t)(jb4 + q4) * 64];
        const float4 w = *reinterpret_cast<const float4*>(&sw[wv][q4 * 4]);
        acc = fmaf(w.x, bl(u.x), fmaf(w.y, bh_(u.x),
              fmaf(w.z, bl(u.y), fmaf(w.w, bh_(u.y), acc))));
    }

    const size_t pidx = ((size_t)bh * L_ + i) * 8 + t;
    pacc[pidx * 64 + lane] = acc;
    if (lane == 0) { pm[pidx] = m; pl[pidx] = l; }
}

// ---------------------------------------------------------------------------
// Combine partials (<=8 tiles per row) + output projection + residual.
__global__ __launch_bounds__(256) void out_comb(
        const float* __restrict__ pm, const float* __restrict__ pl,
        const float* __restrict__ pacc, const int* __restrict__ c,
        const float* __restrict__ Wo, const float* __restrict__ q,
        float* __restrict__ out) {
    __shared__ __align__(16) float xr[4][DM_];
    const int tid = threadIdx.x;
    const int r4 = tid >> 6, d = tid & 63;
    const int row0 = blockIdx.x * 4;
    const int row = row0 + r4;
    const int b = row >> 9, i = row & (L_ - 1);
    const bool vi = (c[row] < T_);
    const int nt = (i >> 6) + 1;
#pragma unroll
    for (int h = 0; h < H_; ++h) {
        const int bh = b * H_ + h;
        const size_t p0 = ((size_t)bh * L_ + i) * 8;
        float M = -INFINITY;
        for (int t = 0; t < nt; ++t) M = fmaxf(M, pm[p0 + t]);
        float l = 0.0f, a = 0.0f;
        for (int t = 0; t < nt; ++t) {
            const float e = __expf(pm[p0 + t] - M);
            l = fmaf(pl[p0 + t], e, l);
            a = fmaf(pacc[(p0 + t) * 64 + d], e, a);
        }
        xr[r4][h * 64 + d] = vi ? a / l : 0.0f;
    }
    __syncthreads();
    float acc[4] = {0, 0, 0, 0};
#pragma unroll 4
    for (int kk = 0; kk < DM_; ++kk) {
        const float w = Wo[(size_t)kk * DM_ + tid];
#pragma unroll
        for (int r = 0; r < 4; ++r) acc[r] = fmaf(xr[r][kk], w, acc[r]);
    }
#pragma unroll
    for (int r = 0; r < 4; ++r)
        out[(size_t)(row0 + r) * DM_ + tid] = acc[r] + q[(size_t)(row0 + r) * DM_ + tid];
}

// ---------------------------------------------------------------------------
extern "C" void kernel_launch(void* const* d_in, const int* in_sizes, int n_in,
                              void* d_out, int out_size, void* d_ws, size_t ws_size,
                              hipStream_t stream) {
    const float* q    = (const float*)d_in[0];
    const float* k    = (const float*)d_in[1];
    const float* v    = (const float*)d_in[2];
    const float* t_in = (const float*)d_in[3];
    const int*   c    = (const int*)d_in[4];
    // d_in[5] = mask: fixed causal triu, never read
    const float* ln_g = (const float*)d_in[6];
    const float* ln_b = (const float*)d_in[7];
    const float* Wq   = (const float*)d_in[8];
    const float* Wk   = (const float*)d_in[9];
    const float* Wv   = (const float*)d_in[10];
    const float* Wo   = (const float*)d_in[11];
    const float* W0   = (const float*)d_in[12];
    const float* b0   = (const float*)d_in[13];
    const float* W1   = (const float*)d_in[14];
    const float* b1   = (const float*)d_in[15];
    const float* Wf   = (const float*)d_in[16];
    const float* bf   = (const float*)d_in[17];
    float* outp = (float*)d_out;

    const size_t SZ = (size_t)B_ * L_ * DM_;   // 262144 floats
    float* ws = (float*)d_ws;
    float* qh   = ws;                          // 262144 f
    float* khT  = ws + SZ;                     // 262144 f
    uint*  vh4  = (uint*)(ws + 2 * SZ);        // 131072 u32
    float* pm   = ws + 2 * SZ + 131072;        // 32768 f
    float* pl   = pm + 32768;                  // 32768 f
    float* pacc = pl + 32768;                  // 2097152 f
    float* pkT  = pacc + 2097152;              // 2097152 f (8 MB)

    fused_prep<<<dim3(1536), dim3(256), 0, stream>>>(
        q, k, v, ln_g, ln_b, Wq, Wk, Wv, t_in, c,
        W0, b0, W1, b1, Wf, bf, qh, khT, vh4, pkT);
    attn_tile<<<dim3(9216), dim3(128), 0, stream>>>(
        qh, khT, vh4, t_in, c, W0, b0, W1, b1, Wf, bf, pkT, pm, pl, pacc);
    out_comb<<<dim3(256), dim3(256), 0, stream>>>(pm, pl, pacc, c, Wo, q, outp);
}